// Round 10
// baseline (415.737 us; speedup 1.0000x reference)
//
#include <hip/hip_runtime.h>
#include <hip/hip_bf16.h>

// bf16 MFMA fragment types (gfx950: 16x16x32, 8 bf16 inputs / 4 f32 acc per lane)
typedef __attribute__((ext_vector_type(8))) short bf16x8;
typedef __attribute__((ext_vector_type(4))) float f32x4;

#define DD 128

// Native bf16 convert (RNE) — compiler emits v_cvt_pk_bf16_f32 pairs.
static __device__ __forceinline__ unsigned short f2bf(float f) {
    __bf16 h = (__bf16)f;
    return __builtin_bit_cast(unsigned short, h);
}
static __device__ __forceinline__ unsigned int pk2bf(float lo, float hi) {
    return ((unsigned int)f2bf(hi) << 16) | (unsigned int)f2bf(lo);
}
static __device__ __forceinline__ float bf2f(unsigned short h) {
    unsigned int u = ((unsigned int)h) << 16;
    return __builtin_bit_cast(float, u);
}

// LDS-only barrier: drains LDS ops but NOT vmcnt.
static __device__ __forceinline__ void lds_barrier() {
    asm volatile("s_waitcnt lgkmcnt(0)" ::: "memory");
    __builtin_amdgcn_s_barrier();
    asm volatile("" ::: "memory");
}
// Within-wave LDS fence (wave-synchronous lanes exchange via LDS, no s_barrier).
static __device__ __forceinline__ void lds_fence() {
    asm volatile("s_waitcnt lgkmcnt(0)" ::: "memory");
}

// -------- weight conversion (6 mats fp32->bf16) FUSED with dst histogram --------
__global__ __launch_bounds__(256) void k_convert_hist(
    const float* __restrict__ w0, const float* __restrict__ w1,
    const float* __restrict__ w2, const float* __restrict__ w3,
    const float* __restrict__ w4, const float* __restrict__ w5,
    unsigned short* __restrict__ wbf,
    const int* __restrict__ dst, int* __restrict__ counts, int nE, int use_perm) {
    int i = blockIdx.x * blockDim.x + threadIdx.x;
    if (i < 6 * 16384) {
        int m = i >> 14, k = i & 16383;
        const float* s = (m == 0) ? w0 : (m == 1) ? w1 : (m == 2) ? w2 : (m == 3) ? w3
                         : (m == 4) ? w4 : w5;
        wbf[i] = f2bf(s[k]);
    }
    if (use_perm)
        for (int e = i; e < nE; e += gridDim.x * blockDim.x)
            atomicAdd(&counts[dst[e]], 1);
}

// -------- hierarchical exclusive scan: counts -> cursor (2 dispatches) --------
__global__ __launch_bounds__(256) void k_scanA(const int* __restrict__ counts,
                                               int* __restrict__ cursor,
                                               int* __restrict__ partials, int nN) {
    __shared__ int ps[256];
    const int tid = threadIdx.x;
    const int i = blockIdx.x * 256 + tid;
    int v = (i < nN) ? counts[i] : 0;
    ps[tid] = v;
    __syncthreads();
    for (int off = 1; off < 256; off <<= 1) {
        int add = (tid >= off) ? ps[tid - off] : 0;
        __syncthreads();
        ps[tid] += add;
        __syncthreads();
    }
    if (i < nN) cursor[i] = ps[tid] - v;          // exclusive within block
    if (tid == 255) partials[blockIdx.x] = ps[255];
}

__global__ __launch_bounds__(256) void k_scanB(int* __restrict__ cursor,
                                               const int* __restrict__ partials,
                                               int nN, int nB) {
    __shared__ int ps[256];
    const int tid = threadIdx.x;
    int v = 0;
    for (int j = tid; j < blockIdx.x; j += 256) v += partials[j];  // blocks before me
    ps[tid] = v;
    __syncthreads();
    for (int off = 1; off < 256; off <<= 1) {
        int add = (tid >= off) ? ps[tid - off] : 0;
        __syncthreads();
        ps[tid] += add;
        __syncthreads();
    }
    const int offset = ps[255];
    const int i = blockIdx.x * 256 + tid;
    if (i < nN) cursor[i] += offset;
}

// ---------------- node pooling FUSED with perm-scatter ----------------
__global__ __launch_bounds__(256, 3) void k_nodes(
    const float* __restrict__ V, const unsigned short* __restrict__ wbf,
    const float* __restrict__ bp1, const float* __restrict__ bp2,
    unsigned short* __restrict__ Vp, int nN, int nTiles,
    const int* __restrict__ dst, int* __restrict__ cursor,
    int* __restrict__ perm, int nE, int use_perm)
{
    if (use_perm)
        for (int e = blockIdx.x * blockDim.x + threadIdx.x; e < nE; e += gridDim.x * blockDim.x) {
            int pos = atomicAdd(&cursor[dst[e]], 1);
            perm[pos] = e;
        }

    const int lane = threadIdx.x & 63;
    const int wave = threadIdx.x >> 6;
    const int lr = lane & 15, lg = lane >> 4;

    bf16x8 B1[2][4], B2[2][4];
#pragma unroll
    for (int ct = 0; ct < 2; ++ct)
#pragma unroll
        for (int kk = 0; kk < 4; ++kk) {
            int j = wave * 32 + ct * 16 + lr;
            int k0 = kk * 32 + lg * 8;
            B1[ct][kk] = *(const bf16x8*)(wbf + 0 * 16384 + j * DD + k0);
            B2[ct][kk] = *(const bf16x8*)(wbf + 1 * 16384 + j * DD + k0);
        }
    float b1v[2], b2v[2];
#pragma unroll
    for (int ct = 0; ct < 2; ++ct) {
        int c = wave * 32 + ct * 16 + lr;
        b1v[ct] = bp1[c]; b2v[ct] = bp2[c];
    }
    __shared__ alignas(16) unsigned short xb[32][132];

    for (int t = blockIdx.x; t < nTiles; t += gridDim.x) {
        const int r0 = t * 32;
        bf16x8 A[2][4];
#pragma unroll
        for (int rg = 0; rg < 2; ++rg)
#pragma unroll
            for (int kk = 0; kk < 4; ++kk) {
                int row = r0 + rg * 16 + lr; if (row >= nN) row = nN - 1;
                const float4* p = (const float4*)(V + (size_t)row * DD + kk * 32 + lg * 8);
                float4 f0 = p[0], f1 = p[1];
                float v[8] = {f0.x, f0.y, f0.z, f0.w, f1.x, f1.y, f1.z, f1.w};
                bf16x8 a;
#pragma unroll
                for (int e = 0; e < 8; ++e) {
                    float x = v[e];
                    x = x > 0.f ? x : 0.2f * x;
                    a[e] = (short)f2bf(x);
                }
                A[rg][kk] = a;
            }
#pragma unroll
        for (int rg = 0; rg < 2; ++rg)
#pragma unroll
            for (int ct = 0; ct < 2; ++ct) {
                f32x4 acc = {0.f, 0.f, 0.f, 0.f};
#pragma unroll
                for (int kk = 0; kk < 4; ++kk)
                    acc = __builtin_amdgcn_mfma_f32_16x16x32_bf16(A[rg][kk], B1[ct][kk], acc, 0, 0, 0);
#pragma unroll
                for (int r = 0; r < 4; ++r) {
                    float x = acc[r] + b1v[ct];
                    x = x > 0.f ? x : 0.2f * x;
                    xb[rg * 16 + lg * 4 + r][wave * 32 + ct * 16 + lr] = f2bf(x);
                }
            }
        lds_barrier();
        bf16x8 A2[2][4];
#pragma unroll
        for (int rg = 0; rg < 2; ++rg)
#pragma unroll
            for (int kk = 0; kk < 4; ++kk)
                A2[rg][kk] = *(const bf16x8*)&xb[rg * 16 + lr][kk * 32 + lg * 8];
#pragma unroll
        for (int rg = 0; rg < 2; ++rg)
#pragma unroll
            for (int ct = 0; ct < 2; ++ct) {
                f32x4 acc = {0.f, 0.f, 0.f, 0.f};
#pragma unroll
                for (int kk = 0; kk < 4; ++kk)
                    acc = __builtin_amdgcn_mfma_f32_16x16x32_bf16(A2[rg][kk], B2[ct][kk], acc, 0, 0, 0);
#pragma unroll
                for (int r = 0; r < 4; ++r) {
                    int row = r0 + rg * 16 + lg * 4 + r;
                    if (row < nN)
                        Vp[(size_t)row * DD + wave * 32 + ct * 16 + lr] = f2bf(acc[r] + b2v[ct]);
                }
            }
        lds_barrier();
    }
}

// ------- fused edge pipeline (dst-sorted), single-Eb, wave-local reduce -----------
// LDS 50.6 KB/block -> 3 blocks/CU resident (was 60.3 -> 2). Single Eb audit:
// A-reads(t) pre-b1; stage(t+next) post-b1 (writes drain at b2's lgkmcnt);
// next A-reads post-b2. All conflicting pairs barrier-separated.
__global__ __launch_bounds__(256, 2) void k_edges(
    const float* __restrict__ E, const int* __restrict__ src, const int* __restrict__ dst,
    const int* __restrict__ perm, int use_perm,
    const unsigned short* __restrict__ wbf,
    const float* __restrict__ bA1, const float* __restrict__ bA2,
    const float* __restrict__ bB, const float* __restrict__ bC,
    const unsigned short* __restrict__ Vp, float* __restrict__ out, int nE, int nTiles)
{
    const int lane = threadIdx.x & 63;
    const int wave = threadIdx.x >> 6;
    const int lr = lane & 15, lg = lane >> 4;
    const int srow = threadIdx.x >> 3;     // 0..31 staging row
    const int schunk = threadIdx.x & 7;    // 0..7

    bf16x8 B1[2][4], B2[2][4], B3[2][4], B4[2][4];
#pragma unroll
    for (int ct = 0; ct < 2; ++ct)
#pragma unroll
        for (int kk = 0; kk < 4; ++kk) {
            int j = wave * 32 + ct * 16 + lr;
            int k0 = kk * 32 + lg * 8;
            const unsigned short* p = wbf + 2 * 16384 + j * DD + k0;
            B1[ct][kk] = *(const bf16x8*)(p);
            B2[ct][kk] = *(const bf16x8*)(p + 16384);
            B3[ct][kk] = *(const bf16x8*)(p + 32768);
            B4[ct][kk] = *(const bf16x8*)(p + 49152);
        }
    float b1v[2], b2v[2], b3v[2], b4v[2];
#pragma unroll
    for (int ct = 0; ct < 2; ++ct) {
        int c = wave * 32 + ct * 16 + lr;
        b1v[ct] = bA1[c]; b2v[ct] = bA2[c]; b3v[ct] = bB[c]; b4v[ct] = bC[c];
    }
    __shared__ alignas(16) unsigned short xb[2][32][132];
    __shared__ alignas(16) unsigned short Eb[32][132];     // SINGLE buffer
    __shared__ alignas(8)  unsigned short gv[32][140];
    __shared__ alignas(16) float msgw[4][32][34];          // per-wave scratch
    __shared__ int dstb[32];

    const int gstep = gridDim.x;
    int t = blockIdx.x;

    auto pidx = [&](int i) -> int {
        if (i >= nE) i = nE - 1;
        return use_perm ? perm[i] : i;
    };

    // ---- prologue ----
    int pe_t = pidx(t * 32 + srow);
    int pe1  = pidx((t + gstep) * 32 + srow);
    uint2 g0, g1, g2, g3;
    {
        const uint2* vp2 = (const uint2*)(Vp + (size_t)src[pe_t] * DD);
        g0 = vp2[schunk]; g1 = vp2[schunk + 8]; g2 = vp2[schunk + 16]; g3 = vp2[schunk + 24];
    }
    int pd = ((t * 32 + srow) < nE) ? dst[pe_t] : -1;
    float4 pf0, pf1, pf2, pf3;
    {
        const float4* np = (const float4*)(E + (size_t)pe1 * DD + schunk * 16);
        pf0 = np[0]; pf1 = np[1]; pf2 = np[2]; pf3 = np[3];
    }
    {
        const float4* p = (const float4*)(E + (size_t)pe_t * DD + schunk * 16);
        float4 f0 = p[0], f1 = p[1], f2 = p[2], f3 = p[3];
        uint4 w0 = make_uint4(pk2bf(f0.x, f0.y), pk2bf(f0.z, f0.w),
                              pk2bf(f1.x, f1.y), pk2bf(f1.z, f1.w));
        uint4 w1 = make_uint4(pk2bf(f2.x, f2.y), pk2bf(f2.z, f2.w),
                              pk2bf(f3.x, f3.y), pk2bf(f3.z, f3.w));
        uint4* wp = (uint4*)&Eb[srow][schunk * 16];
        wp[0] = w0; wp[1] = w1;
    }
    lds_barrier();

    for (; t < nTiles; t += gstep) {
        // --- A-frags from Eb (consumed fully before b1) ---
        bf16x8 A[2][4];
#pragma unroll
        for (int rg = 0; rg < 2; ++rg)
#pragma unroll
            for (int kk = 0; kk < 4; ++kk)
                A[rg][kk] = *(const bf16x8*)&Eb[rg * 16 + lr][kk * 32 + lg * 8];
        // G1: x1 = relu(E@WA1^T + bA1) -> xb[0]
#pragma unroll
        for (int rg = 0; rg < 2; ++rg)
#pragma unroll
            for (int ct = 0; ct < 2; ++ct) {
                f32x4 acc = {0.f, 0.f, 0.f, 0.f};
                __builtin_amdgcn_s_setprio(1);
#pragma unroll
                for (int kk = 0; kk < 4; ++kk)
                    acc = __builtin_amdgcn_mfma_f32_16x16x32_bf16(A[rg][kk], B1[ct][kk], acc, 0, 0, 0);
                __builtin_amdgcn_s_setprio(0);
#pragma unroll
                for (int r = 0; r < 4; ++r) {
                    float x = fmaxf(acc[r] + b1v[ct], 0.f);
                    xb[0][rg * 16 + lg * 4 + r][wave * 32 + ct * 16 + lr] = f2bf(x);
                }
            }
        lds_barrier();                      // b1
        // park gathered rows + dst ids
        *(uint2*)&gv[srow][schunk * 4]      = g0;
        *(uint2*)&gv[srow][schunk * 4 + 32] = g1;
        *(uint2*)&gv[srow][schunk * 4 + 64] = g2;
        *(uint2*)&gv[srow][schunk * 4 + 96] = g3;
        if (schunk == 0) dstb[srow] = pd;
        // stage E[next iter] (pf loaded one iter ago) -> Eb; drains at b2;
        // next iter's A-reads are post-b2. Single buffer safe.
        {
            uint4 w0 = make_uint4(pk2bf(pf0.x, pf0.y), pk2bf(pf0.z, pf0.w),
                                  pk2bf(pf1.x, pf1.y), pk2bf(pf1.z, pf1.w));
            uint4 w1 = make_uint4(pk2bf(pf2.x, pf2.y), pk2bf(pf2.z, pf2.w),
                                  pk2bf(pf3.x, pf3.y), pk2bf(pf3.z, pf3.w));
            uint4* wp = (uint4*)&Eb[srow][schunk * 16];
            wp[0] = w0; wp[1] = w1;
        }
        // ===== safe zone: issue future-tile global loads =====
        int pe2 = pidx((t + 2 * gstep) * 32 + srow);
        float4 nf0, nf1, nf2, nf3;
        {
            const float4* np = (const float4*)(E + (size_t)pe2 * DD + schunk * 16);
            nf0 = np[0]; nf1 = np[1]; nf2 = np[2]; nf3 = np[3];
        }
        {
            int sl = src[pe1];
            const uint2* nvp2 = (const uint2*)(Vp + (size_t)sl * DD);
            g0 = nvp2[schunk]; g1 = nvp2[schunk + 8]; g2 = nvp2[schunk + 16]; g3 = nvp2[schunk + 24];
        }
        int pdn = (((t + gstep) * 32 + srow) < nE) ? dst[pe1] : -1;
        // ===== end safe zone =====
        // G2: x = x1@WA2^T + bA2 -> xb[1]
        bf16x8 A2[2][4];
#pragma unroll
        for (int rg = 0; rg < 2; ++rg)
#pragma unroll
            for (int kk = 0; kk < 4; ++kk)
                A2[rg][kk] = *(const bf16x8*)&xb[0][rg * 16 + lr][kk * 32 + lg * 8];
#pragma unroll
        for (int rg = 0; rg < 2; ++rg)
#pragma unroll
            for (int ct = 0; ct < 2; ++ct) {
                f32x4 acc = {0.f, 0.f, 0.f, 0.f};
                __builtin_amdgcn_s_setprio(1);
#pragma unroll
                for (int kk = 0; kk < 4; ++kk)
                    acc = __builtin_amdgcn_mfma_f32_16x16x32_bf16(A2[rg][kk], B2[ct][kk], acc, 0, 0, 0);
                __builtin_amdgcn_s_setprio(0);
#pragma unroll
                for (int r = 0; r < 4; ++r)
                    xb[1][rg * 16 + lg * 4 + r][wave * 32 + ct * 16 + lr] = f2bf(acc[r] + b2v[ct]);
            }
        lds_barrier();                      // b2 (drains Eb stage + xb[1])
        // G3/G4: scale/shift; msg -> per-wave LDS scratch
        bf16x8 A3[2][4];
#pragma unroll
        for (int rg = 0; rg < 2; ++rg)
#pragma unroll
            for (int kk = 0; kk < 4; ++kk)
                A3[rg][kk] = *(const bf16x8*)&xb[1][rg * 16 + lr][kk * 32 + lg * 8];
#pragma unroll
        for (int rg = 0; rg < 2; ++rg)
#pragma unroll
            for (int ct = 0; ct < 2; ++ct) {
                f32x4 aB = {0.f, 0.f, 0.f, 0.f}, aC = {0.f, 0.f, 0.f, 0.f};
                __builtin_amdgcn_s_setprio(1);
#pragma unroll
                for (int kk = 0; kk < 4; ++kk) {
                    aB = __builtin_amdgcn_mfma_f32_16x16x32_bf16(A3[rg][kk], B3[ct][kk], aB, 0, 0, 0);
                    aC = __builtin_amdgcn_mfma_f32_16x16x32_bf16(A3[rg][kk], B4[ct][kk], aC, 0, 0, 0);
                }
                __builtin_amdgcn_s_setprio(0);
#pragma unroll
                for (int r = 0; r < 4; ++r) {
                    float e = __expf(-(aB[r] + b3v[ct]));
                    float sc = __builtin_amdgcn_rcpf(1.f + e);
                    float sh = aC[r] + b4v[ct];
                    float v = bf2f(gv[rg * 16 + lg * 4 + r][wave * 32 + ct * 16 + lr]);
                    msgw[wave][rg * 16 + lg * 4 + r][ct * 16 + lr] = sc * v + sh;
                }
            }
        lds_fence();   // within-wave msgw visibility (wave-synchronous)
        // Wave-local segmented reduction: 2 lanes per column (halves), 16 sorted
        // rows each, one atomic per (run, col).
        {
            const int cw = lane & 31;          // wave-local col
            const int half = lane >> 5;        // rows 0-15 / 16-31
            const int col = wave * 32 + cw;
            const int rbase = half * 16;
            float acc = 0.f;
#pragma unroll
            for (int rr = 0; rr < 16; ++rr) {
                const int rrow = rbase + rr;
                acc += msgw[wave][rrow][cw];
                int d = dstb[rrow];
                bool flush = (rr == 15) || (dstb[rrow + 1] != d);
                if (flush) {
                    if (d >= 0)
                        unsafeAtomicAdd(out + (size_t)d * DD + col, acc);
                    acc = 0.f;
                }
            }
        }
        // no loop-end barrier (audited as before; Eb handled via b1/b2 pairing)
        pf0 = nf0; pf1 = nf1; pf2 = nf2; pf3 = nf3;
        pe1 = pe2; pd = pdn;
    }
}

extern "C" void kernel_launch(void* const* d_in, const int* in_sizes, int n_in,
                              void* d_out, int out_size, void* d_ws, size_t ws_size,
                              hipStream_t stream) {
    const float* V   = (const float*)d_in[0];
    const float* E   = (const float*)d_in[1];
    const int*   src = (const int*)d_in[2];
    const int*   dst = (const int*)d_in[3];
    const float* Wp1 = (const float*)d_in[4];  const float* bp1 = (const float*)d_in[5];
    const float* Wp2 = (const float*)d_in[6];  const float* bp2 = (const float*)d_in[7];
    const float* WA1 = (const float*)d_in[8];  const float* bA1 = (const float*)d_in[9];
    const float* WA2 = (const float*)d_in[10]; const float* bA2 = (const float*)d_in[11];
    const float* WB  = (const float*)d_in[12]; const float* bB  = (const float*)d_in[13];
    const float* WC  = (const float*)d_in[14]; const float* bC  = (const float*)d_in[15];
    float* out = (float*)d_out;

    const int nN = in_sizes[0] / DD;
    const int nE = in_sizes[1] / DD;
    const int nTilesN = (nN + 31) / 32;
    const int nTilesE = (nE + 31) / 32;
    const int nB = (nN + 255) / 256;          // scan blocks

    // ws layout
    char* wsb = (char*)d_ws;
    unsigned short* wbf = (unsigned short*)wsb;                        // 196608 B
    unsigned short* Vp  = (unsigned short*)(wsb + 196608);             // nN*256 B
    size_t off_counts = 196608 + (size_t)nN * 256;
    int* counts   = (int*)(wsb + off_counts);                          // nN*4
    int* cursor   = (int*)(wsb + off_counts + (size_t)nN * 4);         // nN*4
    int* perm     = (int*)(wsb + off_counts + (size_t)nN * 8);         // nE*4
    int* partials = (int*)(wsb + off_counts + (size_t)nN * 8 + (size_t)nE * 4); // nB*4
    size_t ws_need = off_counts + (size_t)nN * 8 + (size_t)nE * 4 + (size_t)nB * 4;
    int use_perm = (ws_size >= ws_need) ? 1 : 0;

    hipMemsetAsync(d_out, 0, (size_t)out_size * sizeof(float), stream);
    if (use_perm) hipMemsetAsync(counts, 0, (size_t)nN * 4, stream);

    k_convert_hist<<<1024, 256, 0, stream>>>(Wp1, Wp2, WA1, WA2, WB, WC, wbf,
                                             dst, counts, nE, use_perm);
    if (use_perm) {
        k_scanA<<<nB, 256, 0, stream>>>(counts, cursor, partials, nN);
        k_scanB<<<nB, 256, 0, stream>>>(cursor, partials, nN, nB);
    }

    int gN = nTilesN < 768 ? nTilesN : 768;
    k_nodes<<<gN, 256, 0, stream>>>(V, wbf, bp1, bp2, Vp, nN, nTilesN,
                                    dst, cursor, perm, nE, use_perm);
    int gE = nTilesE < 768 ? nTilesE : 768;   // 3 blocks/CU resident (LDS 50.6 KB)
    k_edges<<<gE, 256, 0, stream>>>(E, src, dst, perm, use_perm, wbf,
                                    bA1, bA2, bB, bC, Vp, out, nE, nTilesE);
}

// Round 11
// 339.846 us; speedup vs baseline: 1.2233x; 1.2233x over previous
//
#include <hip/hip_runtime.h>
#include <hip/hip_bf16.h>

// bf16 MFMA fragment types (gfx950: 16x16x32, 8 bf16 inputs / 4 f32 acc per lane)
typedef __attribute__((ext_vector_type(8))) short bf16x8;
typedef __attribute__((ext_vector_type(4))) float f32x4;

#define DD 128

// Native bf16 convert (RNE) — compiler emits v_cvt_pk_bf16_f32 pairs.
static __device__ __forceinline__ unsigned short f2bf(float f) {
    __bf16 h = (__bf16)f;
    return __builtin_bit_cast(unsigned short, h);
}
static __device__ __forceinline__ unsigned int pk2bf(float lo, float hi) {
    return ((unsigned int)f2bf(hi) << 16) | (unsigned int)f2bf(lo);
}
static __device__ __forceinline__ float bf2f(unsigned short h) {
    unsigned int u = ((unsigned int)h) << 16;
    return __builtin_bit_cast(float, u);
}

// LDS-only barrier: drains LDS ops but NOT vmcnt.
static __device__ __forceinline__ void lds_barrier() {
    asm volatile("s_waitcnt lgkmcnt(0)" ::: "memory");
    __builtin_amdgcn_s_barrier();
    asm volatile("" ::: "memory");
}
// Within-wave LDS fence (wave-synchronous lanes exchange via LDS, no s_barrier).
static __device__ __forceinline__ void lds_fence() {
    asm volatile("s_waitcnt lgkmcnt(0)" ::: "memory");
}

// -------- weight conversion (6 mats fp32->bf16) FUSED with dst histogram --------
__global__ __launch_bounds__(256) void k_convert_hist(
    const float* __restrict__ w0, const float* __restrict__ w1,
    const float* __restrict__ w2, const float* __restrict__ w3,
    const float* __restrict__ w4, const float* __restrict__ w5,
    unsigned short* __restrict__ wbf,
    const int* __restrict__ dst, int* __restrict__ counts, int nE, int use_perm) {
    int i = blockIdx.x * blockDim.x + threadIdx.x;
    if (i < 6 * 16384) {
        int m = i >> 14, k = i & 16383;
        const float* s = (m == 0) ? w0 : (m == 1) ? w1 : (m == 2) ? w2 : (m == 3) ? w3
                         : (m == 4) ? w4 : w5;
        wbf[i] = f2bf(s[k]);
    }
    if (use_perm)
        for (int e = i; e < nE; e += gridDim.x * blockDim.x)
            atomicAdd(&counts[dst[e]], 1);
}

// -------- hierarchical exclusive scan: counts -> cursor (2 dispatches) --------
__global__ __launch_bounds__(256) void k_scanA(const int* __restrict__ counts,
                                               int* __restrict__ cursor,
                                               int* __restrict__ partials, int nN) {
    __shared__ int ps[256];
    const int tid = threadIdx.x;
    const int i = blockIdx.x * 256 + tid;
    int v = (i < nN) ? counts[i] : 0;
    ps[tid] = v;
    __syncthreads();
    for (int off = 1; off < 256; off <<= 1) {
        int add = (tid >= off) ? ps[tid - off] : 0;
        __syncthreads();
        ps[tid] += add;
        __syncthreads();
    }
    if (i < nN) cursor[i] = ps[tid] - v;          // exclusive within block
    if (tid == 255) partials[blockIdx.x] = ps[255];
}

__global__ __launch_bounds__(256) void k_scanB(int* __restrict__ cursor,
                                               const int* __restrict__ partials,
                                               int nN, int nB) {
    __shared__ int ps[256];
    const int tid = threadIdx.x;
    int v = 0;
    for (int j = tid; j < blockIdx.x; j += 256) v += partials[j];  // blocks before me
    ps[tid] = v;
    __syncthreads();
    for (int off = 1; off < 256; off <<= 1) {
        int add = (tid >= off) ? ps[tid - off] : 0;
        __syncthreads();
        ps[tid] += add;
        __syncthreads();
    }
    const int offset = ps[255];
    const int i = blockIdx.x * 256 + tid;
    if (i < nN) cursor[i] += offset;
}

// ----- node pooling FUSED with perm-scatter (+ sorted src/dst sidecars) -----
__global__ __launch_bounds__(256, 3) void k_nodes(
    const float* __restrict__ V, const unsigned short* __restrict__ wbf,
    const float* __restrict__ bp1, const float* __restrict__ bp2,
    unsigned short* __restrict__ Vp, int nN, int nTiles,
    const int* __restrict__ src, const int* __restrict__ dst,
    int* __restrict__ cursor, int* __restrict__ perm,
    int* __restrict__ srcS, int* __restrict__ dstS, int nE, int use_perm)
{
    if (use_perm)
        for (int e = blockIdx.x * blockDim.x + threadIdx.x; e < nE; e += gridDim.x * blockDim.x) {
            int d = dst[e];
            int pos = atomicAdd(&cursor[d], 1);
            perm[pos] = e;
            srcS[pos] = src[e];   // sorted sidecars: edges kernel reads these
            dstS[pos] = d;        // coalesced instead of random 4B via perm
        }

    const int lane = threadIdx.x & 63;
    const int wave = threadIdx.x >> 6;
    const int lr = lane & 15, lg = lane >> 4;

    bf16x8 B1[2][4], B2[2][4];
#pragma unroll
    for (int ct = 0; ct < 2; ++ct)
#pragma unroll
        for (int kk = 0; kk < 4; ++kk) {
            int j = wave * 32 + ct * 16 + lr;
            int k0 = kk * 32 + lg * 8;
            B1[ct][kk] = *(const bf16x8*)(wbf + 0 * 16384 + j * DD + k0);
            B2[ct][kk] = *(const bf16x8*)(wbf + 1 * 16384 + j * DD + k0);
        }
    float b1v[2], b2v[2];
#pragma unroll
    for (int ct = 0; ct < 2; ++ct) {
        int c = wave * 32 + ct * 16 + lr;
        b1v[ct] = bp1[c]; b2v[ct] = bp2[c];
    }
    __shared__ alignas(16) unsigned short xb[32][132];

    for (int t = blockIdx.x; t < nTiles; t += gridDim.x) {
        const int r0 = t * 32;
        bf16x8 A[2][4];
#pragma unroll
        for (int rg = 0; rg < 2; ++rg)
#pragma unroll
            for (int kk = 0; kk < 4; ++kk) {
                int row = r0 + rg * 16 + lr; if (row >= nN) row = nN - 1;
                const float4* p = (const float4*)(V + (size_t)row * DD + kk * 32 + lg * 8);
                float4 f0 = p[0], f1 = p[1];
                float v[8] = {f0.x, f0.y, f0.z, f0.w, f1.x, f1.y, f1.z, f1.w};
                bf16x8 a;
#pragma unroll
                for (int e = 0; e < 8; ++e) {
                    float x = v[e];
                    x = x > 0.f ? x : 0.2f * x;
                    a[e] = (short)f2bf(x);
                }
                A[rg][kk] = a;
            }
#pragma unroll
        for (int rg = 0; rg < 2; ++rg)
#pragma unroll
            for (int ct = 0; ct < 2; ++ct) {
                f32x4 acc = {0.f, 0.f, 0.f, 0.f};
#pragma unroll
                for (int kk = 0; kk < 4; ++kk)
                    acc = __builtin_amdgcn_mfma_f32_16x16x32_bf16(A[rg][kk], B1[ct][kk], acc, 0, 0, 0);
#pragma unroll
                for (int r = 0; r < 4; ++r) {
                    float x = acc[r] + b1v[ct];
                    x = x > 0.f ? x : 0.2f * x;
                    xb[rg * 16 + lg * 4 + r][wave * 32 + ct * 16 + lr] = f2bf(x);
                }
            }
        lds_barrier();
        bf16x8 A2[2][4];
#pragma unroll
        for (int rg = 0; rg < 2; ++rg)
#pragma unroll
            for (int kk = 0; kk < 4; ++kk)
                A2[rg][kk] = *(const bf16x8*)&xb[rg * 16 + lr][kk * 32 + lg * 8];
#pragma unroll
        for (int rg = 0; rg < 2; ++rg)
#pragma unroll
            for (int ct = 0; ct < 2; ++ct) {
                f32x4 acc = {0.f, 0.f, 0.f, 0.f};
#pragma unroll
                for (int kk = 0; kk < 4; ++kk)
                    acc = __builtin_amdgcn_mfma_f32_16x16x32_bf16(A2[rg][kk], B2[ct][kk], acc, 0, 0, 0);
#pragma unroll
                for (int r = 0; r < 4; ++r) {
                    int row = r0 + rg * 16 + lg * 4 + r;
                    if (row < nN)
                        Vp[(size_t)row * DD + wave * 32 + ct * 16 + lr] = f2bf(acc[r] + b2v[ct]);
                }
            }
        lds_barrier();
    }
}

// ------- fused edge pipeline (dst-sorted), 2 barriers/tile, wave-local reduce -----
__global__ __launch_bounds__(256, 2) void k_edges(
    const float* __restrict__ E, const int* __restrict__ src, const int* __restrict__ dst,
    const int* __restrict__ perm, const int* __restrict__ srcS, const int* __restrict__ dstS,
    int use_perm,
    const unsigned short* __restrict__ wbf,
    const float* __restrict__ bA1, const float* __restrict__ bA2,
    const float* __restrict__ bB, const float* __restrict__ bC,
    const unsigned short* __restrict__ Vp, float* __restrict__ out, int nE, int nTiles)
{
    const int lane = threadIdx.x & 63;
    const int wave = threadIdx.x >> 6;
    const int lr = lane & 15, lg = lane >> 4;
    const int srow = threadIdx.x >> 3;     // 0..31 staging row
    const int schunk = threadIdx.x & 7;    // 0..7

    bf16x8 B1[2][4], B2[2][4], B3[2][4], B4[2][4];
#pragma unroll
    for (int ct = 0; ct < 2; ++ct)
#pragma unroll
        for (int kk = 0; kk < 4; ++kk) {
            int j = wave * 32 + ct * 16 + lr;
            int k0 = kk * 32 + lg * 8;
            const unsigned short* p = wbf + 2 * 16384 + j * DD + k0;
            B1[ct][kk] = *(const bf16x8*)(p);
            B2[ct][kk] = *(const bf16x8*)(p + 16384);
            B3[ct][kk] = *(const bf16x8*)(p + 32768);
            B4[ct][kk] = *(const bf16x8*)(p + 49152);
        }
    float b1v[2], b2v[2], b3v[2], b4v[2];
#pragma unroll
    for (int ct = 0; ct < 2; ++ct) {
        int c = wave * 32 + ct * 16 + lr;
        b1v[ct] = bA1[c]; b2v[ct] = bA2[c]; b3v[ct] = bB[c]; b4v[ct] = bC[c];
    }
    // Bank-exact pads (R9, verified: conflicts 12.8M -> 5.6M).
    __shared__ alignas(16) unsigned short xb[2][32][132];
    __shared__ alignas(16) unsigned short Eb[2][32][132];
    __shared__ alignas(8)  unsigned short gv[32][140];
    __shared__ alignas(16) float msgw[4][32][34];   // per-wave scratch (no barrier)
    __shared__ int dstb[32];

    const int gstep = gridDim.x;
    int t = blockIdx.x;

    // sorted-position metadata: pe (E row), sl (gather src), pd (dst or -1)
    auto loadMeta = [&](int i, int& pe, int& sl, int& pd) {
        bool valid = (i < nE); if (!valid) i = nE - 1;
        if (use_perm) { pe = perm[i]; sl = srcS[i]; pd = dstS[i]; }
        else          { pe = i;       sl = src[i];  pd = dst[i];  }
        if (!valid) pd = -1;
    };

    // ---- prologue ----
    int pe_t, sl_t, pd;
    loadMeta(t * 32 + srow, pe_t, sl_t, pd);
    int peN, slN, pdN;
    loadMeta((t + gstep) * 32 + srow, peN, slN, pdN);
    uint2 g0, g1, g2, g3;
    {
        const uint2* vp2 = (const uint2*)(Vp + (size_t)sl_t * DD);
        g0 = vp2[schunk]; g1 = vp2[schunk + 8]; g2 = vp2[schunk + 16]; g3 = vp2[schunk + 24];
    }
    float4 pf0, pf1, pf2, pf3;
    {
        const float4* np = (const float4*)(E + (size_t)peN * DD + schunk * 16);
        pf0 = np[0]; pf1 = np[1]; pf2 = np[2]; pf3 = np[3];
    }
    {
        const float4* p = (const float4*)(E + (size_t)pe_t * DD + schunk * 16);
        float4 f0 = p[0], f1 = p[1], f2 = p[2], f3 = p[3];
        uint4 w0 = make_uint4(pk2bf(f0.x, f0.y), pk2bf(f0.z, f0.w),
                              pk2bf(f1.x, f1.y), pk2bf(f1.z, f1.w));
        uint4 w1 = make_uint4(pk2bf(f2.x, f2.y), pk2bf(f2.z, f2.w),
                              pk2bf(f3.x, f3.y), pk2bf(f3.z, f3.w));
        uint4* wp = (uint4*)&Eb[0][srow][schunk * 16];
        wp[0] = w0; wp[1] = w1;
    }
    lds_barrier();
    int cur = 0;

    for (; t < nTiles; t += gstep) {
        // --- A-frags from Eb[cur] ---
        bf16x8 A[2][4];
#pragma unroll
        for (int rg = 0; rg < 2; ++rg)
#pragma unroll
            for (int kk = 0; kk < 4; ++kk)
                A[rg][kk] = *(const bf16x8*)&Eb[cur][rg * 16 + lr][kk * 32 + lg * 8];
        // G1: x1 = relu(E@WA1^T + bA1) -> xb[0]
#pragma unroll
        for (int rg = 0; rg < 2; ++rg)
#pragma unroll
            for (int ct = 0; ct < 2; ++ct) {
                f32x4 acc = {0.f, 0.f, 0.f, 0.f};
                __builtin_amdgcn_s_setprio(1);
#pragma unroll
                for (int kk = 0; kk < 4; ++kk)
                    acc = __builtin_amdgcn_mfma_f32_16x16x32_bf16(A[rg][kk], B1[ct][kk], acc, 0, 0, 0);
                __builtin_amdgcn_s_setprio(0);
#pragma unroll
                for (int r = 0; r < 4; ++r) {
                    float x = fmaxf(acc[r] + b1v[ct], 0.f);
                    xb[0][rg * 16 + lg * 4 + r][wave * 32 + ct * 16 + lr] = f2bf(x);
                }
            }
        lds_barrier();                      // b1
        // park gathered rows + dst ids (prior tile's epilogue used neither)
        *(uint2*)&gv[srow][schunk * 4]      = g0;
        *(uint2*)&gv[srow][schunk * 4 + 32] = g1;
        *(uint2*)&gv[srow][schunk * 4 + 64] = g2;
        *(uint2*)&gv[srow][schunk * 4 + 96] = g3;
        if (schunk == 0) dstb[srow] = pd;
        // stage E[t+gstep] (pf loaded one tile ago) -> Eb[cur^1]; read after b2
        {
            uint4 w0 = make_uint4(pk2bf(pf0.x, pf0.y), pk2bf(pf0.z, pf0.w),
                                  pk2bf(pf1.x, pf1.y), pk2bf(pf1.z, pf1.w));
            uint4 w1 = make_uint4(pk2bf(pf2.x, pf2.y), pk2bf(pf2.z, pf2.w),
                                  pk2bf(pf3.x, pf3.y), pk2bf(pf3.z, pf3.w));
            uint4* wp = (uint4*)&Eb[cur ^ 1][srow][schunk * 16];
            wp[0] = w0; wp[1] = w1;
        }
        // ===== safe zone: issue future-tile global loads =====
        int pe2, sl2, pd2;
        loadMeta((t + 2 * gstep) * 32 + srow, pe2, sl2, pd2);
        float4 nf0, nf1, nf2, nf3;
        {
            const float4* np = (const float4*)(E + (size_t)pe2 * DD + schunk * 16);
            nf0 = np[0]; nf1 = np[1]; nf2 = np[2]; nf3 = np[3];
        }
        {
            const uint2* nvp2 = (const uint2*)(Vp + (size_t)slN * DD);
            g0 = nvp2[schunk]; g1 = nvp2[schunk + 8]; g2 = nvp2[schunk + 16]; g3 = nvp2[schunk + 24];
        }
        // ===== end safe zone =====
        // G2: x = x1@WA2^T + bA2 -> xb[1]
        bf16x8 A2[2][4];
#pragma unroll
        for (int rg = 0; rg < 2; ++rg)
#pragma unroll
            for (int kk = 0; kk < 4; ++kk)
                A2[rg][kk] = *(const bf16x8*)&xb[0][rg * 16 + lr][kk * 32 + lg * 8];
#pragma unroll
        for (int rg = 0; rg < 2; ++rg)
#pragma unroll
            for (int ct = 0; ct < 2; ++ct) {
                f32x4 acc = {0.f, 0.f, 0.f, 0.f};
                __builtin_amdgcn_s_setprio(1);
#pragma unroll
                for (int kk = 0; kk < 4; ++kk)
                    acc = __builtin_amdgcn_mfma_f32_16x16x32_bf16(A2[rg][kk], B2[ct][kk], acc, 0, 0, 0);
                __builtin_amdgcn_s_setprio(0);
#pragma unroll
                for (int r = 0; r < 4; ++r)
                    xb[1][rg * 16 + lg * 4 + r][wave * 32 + ct * 16 + lr] = f2bf(acc[r] + b2v[ct]);
            }
        lds_barrier();                      // b2 (covers Eb[cur^1] stage -> t+1 reads)
        // G3/G4: scale/shift; msg -> per-wave LDS scratch
        bf16x8 A3[2][4];
#pragma unroll
        for (int rg = 0; rg < 2; ++rg)
#pragma unroll
            for (int kk = 0; kk < 4; ++kk)
                A3[rg][kk] = *(const bf16x8*)&xb[1][rg * 16 + lr][kk * 32 + lg * 8];
#pragma unroll
        for (int rg = 0; rg < 2; ++rg)
#pragma unroll
            for (int ct = 0; ct < 2; ++ct) {
                f32x4 aB = {0.f, 0.f, 0.f, 0.f}, aC = {0.f, 0.f, 0.f, 0.f};
                __builtin_amdgcn_s_setprio(1);
#pragma unroll
                for (int kk = 0; kk < 4; ++kk) {
                    aB = __builtin_amdgcn_mfma_f32_16x16x32_bf16(A3[rg][kk], B3[ct][kk], aB, 0, 0, 0);
                    aC = __builtin_amdgcn_mfma_f32_16x16x32_bf16(A3[rg][kk], B4[ct][kk], aC, 0, 0, 0);
                }
                __builtin_amdgcn_s_setprio(0);
#pragma unroll
                for (int r = 0; r < 4; ++r) {
                    float e = __expf(-(aB[r] + b3v[ct]));
                    float sc = __builtin_amdgcn_rcpf(1.f + e);
                    float sh = aC[r] + b4v[ct];
                    float v = bf2f(gv[rg * 16 + lg * 4 + r][wave * 32 + ct * 16 + lr]);
                    msgw[wave][rg * 16 + lg * 4 + r][ct * 16 + lr] = sc * v + sh;
                }
            }
        lds_fence();   // within-wave msgw visibility (wave-synchronous)
        // Wave-local segmented reduction: 2 lanes per column (halves), 16 sorted
        // rows each, one atomic per (run, col).
        {
            const int cw = lane & 31;          // wave-local col
            const int half = lane >> 5;        // rows 0-15 / 16-31
            const int col = wave * 32 + cw;
            const int rbase = half * 16;
            float acc = 0.f;
#pragma unroll
            for (int rr = 0; rr < 16; ++rr) {
                const int rrow = rbase + rr;
                acc += msgw[wave][rrow][cw];
                int d = dstb[rrow];
                bool flush = (rr == 15) || (dstb[rrow + 1] != d);
                if (flush) {
                    if (d >= 0)
                        unsafeAtomicAdd(out + (size_t)d * DD + col, acc);
                    acc = 0.f;
                }
            }
        }
        // no loop-end barrier (audited: xb[0] rewritten only after b1 of t+1;
        // Eb[cur^1] RAW covered by b2; msgw wave-private; gv/dstb post-b1(t+1)).
        cur ^= 1;
        pf0 = nf0; pf1 = nf1; pf2 = nf2; pf3 = nf3;
        pd = pdN; pdN = pd2; slN = sl2;
    }
}

extern "C" void kernel_launch(void* const* d_in, const int* in_sizes, int n_in,
                              void* d_out, int out_size, void* d_ws, size_t ws_size,
                              hipStream_t stream) {
    const float* V   = (const float*)d_in[0];
    const float* E   = (const float*)d_in[1];
    const int*   src = (const int*)d_in[2];
    const int*   dst = (const int*)d_in[3];
    const float* Wp1 = (const float*)d_in[4];  const float* bp1 = (const float*)d_in[5];
    const float* Wp2 = (const float*)d_in[6];  const float* bp2 = (const float*)d_in[7];
    const float* WA1 = (const float*)d_in[8];  const float* bA1 = (const float*)d_in[9];
    const float* WA2 = (const float*)d_in[10]; const float* bA2 = (const float*)d_in[11];
    const float* WB  = (const float*)d_in[12]; const float* bB  = (const float*)d_in[13];
    const float* WC  = (const float*)d_in[14]; const float* bC  = (const float*)d_in[15];
    float* out = (float*)d_out;

    const int nN = in_sizes[0] / DD;
    const int nE = in_sizes[1] / DD;
    const int nTilesN = (nN + 31) / 32;
    const int nTilesE = (nE + 31) / 32;
    const int nB = (nN + 255) / 256;          // scan blocks

    // ws layout
    char* wsb = (char*)d_ws;
    unsigned short* wbf = (unsigned short*)wsb;                        // 196608 B
    unsigned short* Vp  = (unsigned short*)(wsb + 196608);             // nN*256 B
    size_t off = 196608 + (size_t)nN * 256;
    int* counts   = (int*)(wsb + off); off += (size_t)nN * 4;
    int* cursor   = (int*)(wsb + off); off += (size_t)nN * 4;
    int* perm     = (int*)(wsb + off); off += (size_t)nE * 4;
    int* srcS     = (int*)(wsb + off); off += (size_t)nE * 4;
    int* dstS     = (int*)(wsb + off); off += (size_t)nE * 4;
    int* partials = (int*)(wsb + off); off += (size_t)nB * 4;
    int use_perm = (ws_size >= off) ? 1 : 0;

    hipMemsetAsync(d_out, 0, (size_t)out_size * sizeof(float), stream);
    if (use_perm) hipMemsetAsync(counts, 0, (size_t)nN * 4, stream);

    k_convert_hist<<<1024, 256, 0, stream>>>(Wp1, Wp2, WA1, WA2, WB, WC, wbf,
                                             dst, counts, nE, use_perm);
    if (use_perm) {
        k_scanA<<<nB, 256, 0, stream>>>(counts, cursor, partials, nN);
        k_scanB<<<nB, 256, 0, stream>>>(cursor, partials, nN, nB);
    }

    int gN = nTilesN < 768 ? nTilesN : 768;
    k_nodes<<<gN, 256, 0, stream>>>(V, wbf, bp1, bp2, Vp, nN, nTilesN,
                                    src, dst, cursor, perm, srcS, dstS, nE, use_perm);
    int gE = nTilesE < 512 ? nTilesE : 512;   // 2 blocks/CU resident, persistent
    k_edges<<<gE, 256, 0, stream>>>(E, src, dst, perm, srcS, dstS, use_perm, wbf,
                                    bA1, bA2, bB, bC, Vp, out, nE, nTilesE);
}